// Round 3
// baseline (153.499 us; speedup 1.0000x reference)
//
#include <hip/hip_runtime.h>
#include <cstdint>

// =====================================================================
// MultiHeadAttention_84576495993495  (round 3)
//
// Algebraic collapse: einsum('bhqk,bhvo->bhvo', attn, v) sums attn over
// BOTH q and k; softmax rows sum to 1 -> factor is exactly S=2048.
//   final = x @ (2048*Wp@Wv)^T + (2048*Wp@bv + bp)
// Wq/bq/Wk/bk unused.
//
// R3 changes (gemm2 was HBM-fetch-bound from A re-streaming):
//   - GEMM tile BM=64 x BN=256 (A-refetch 16x -> 4x), 4 waves of 64x64
//   - XCD-aware block swizzle on gemm2: each XCD (id%8) owns a contiguous
//     16-m-panel range (2MB of A, L2-resident) -> A fetched ~once from HBM
//   - gemm1 uses the same template (grid 16x4x4 split-K)
// =====================================================================

typedef unsigned short u16;
typedef __bf16 bf16x8 __attribute__((ext_vector_type(8)));
typedef float f32x4 __attribute__((ext_vector_type(4)));

__device__ __forceinline__ u16 f2bf(float f) {
  // round-to-nearest-even f32 -> bf16 bits (finite inputs)
  unsigned int u = __float_as_uint(f);
  u += 0x7fffu + ((u >> 16) & 1u);
  return (u16)(u >> 16);
}

// async global->LDS 16B copy; LDS dest = wave-uniform base + lane*16
__device__ __forceinline__ void load16(const void* g, void* l) {
  auto gp = (const __attribute__((address_space(1))) unsigned int*)(uintptr_t)g;
  auto lp = (__attribute__((address_space(3))) unsigned int*)(unsigned int)(uintptr_t)l;
  __builtin_amdgcn_global_load_lds(gp, lp, 16, 0, 0);
}

// ---------------------------------------------------------------------
// Fused prep. Block ranges:
//   [0,8192)      conv x   f32->bf16 (4 elem/thread)
//   [8192,9216)   conv Wp  f32->bf16
//   [9216,10240)  transpose+conv Wv -> Wv^T bf16 (32x32 tiles)
//   [10240,10496) cv[n] = 2048*dot(Wp[n,:],bv) + bp[n]
__global__ void k_prep(const float* __restrict__ x, const float* __restrict__ Wv,
                       const float* __restrict__ bv, const float* __restrict__ Wp,
                       const float* __restrict__ bp, u16* __restrict__ xb,
                       u16* __restrict__ wpb, u16* __restrict__ wvtb,
                       float* __restrict__ cv) {
  __shared__ float tile[32][33];
  const int b = blockIdx.x;
  const int tid = threadIdx.x;
  if (b < 9216) {  // conversions
    const float* src = (b < 8192) ? x : Wp;
    u16* dst = (b < 8192) ? xb : wpb;
    const long base = (long)((b < 8192) ? b : (b - 8192)) * 1024 + tid * 4;
    const float4 v = *(const float4*)(src + base);
    ushort4 o;
    o.x = f2bf(v.x); o.y = f2bf(v.y); o.z = f2bf(v.z); o.w = f2bf(v.w);
    *(ushort4*)(dst + base) = o;
  } else if (b < 10240) {  // transpose Wv
    const int tb = b - 9216;
    const int bi = (tb & 31) * 32;   // output row block (i)
    const int bj = (tb >> 5) * 32;   // output col block (j) = src row block
    const int tx = tid & 31;
    const int ty = tid >> 5;  // 0..7
    for (int r = ty; r < 32; r += 8)
      tile[r][tx] = Wv[(long)(bj + r) * 1024 + bi + tx];
    __syncthreads();
    for (int r = ty; r < 32; r += 8)
      wvtb[(long)(bi + r) * 1024 + bj + tx] = f2bf(tile[tx][r]);
  } else {  // bias fold
    const int row = (b - 10240) * 4 + (tid >> 6);
    const int lane = tid & 63;
    const float* w = Wp + (long)row * 1024;
    float s = 0.f;
    for (int j = lane; j < 1024; j += 64) s += w[j] * bv[j];
    for (int off = 32; off; off >>= 1) s += __shfl_down(s, off, 64);
    if (lane == 0) cv[row] = 2048.f * s + bp[row];
  }
}

// ---------------------------------------------------------------------
// reduce 4 split-K fp32 partial slabs -> bf16, *2048
__global__ void k_reduce(const float* __restrict__ p, u16* __restrict__ dst) {
  const long i = (long)(blockIdx.x * 256 + threadIdx.x) * 4;
  const float4 a = *(const float4*)(p + i);
  const float4 b = *(const float4*)(p + 1048576 + i);
  const float4 c = *(const float4*)(p + 2097152 + i);
  const float4 d = *(const float4*)(p + 3145728 + i);
  ushort4 o;
  o.x = f2bf((a.x + b.x + c.x + d.x) * 2048.f);
  o.y = f2bf((a.y + b.y + c.y + d.y) * 2048.f);
  o.z = f2bf((a.z + b.z + c.z + d.z) * 2048.f);
  o.w = f2bf((a.w + b.w + c.w + d.w) * 2048.f);
  *(ushort4*)(dst + i) = o;
}

// ---------------------------------------------------------------------
// NT bf16 GEMM: Out[M,N] (+bias) = A[M,K] @ B[N,K]^T
// BM=64, BN=256, BK=32. 256 threads = 4 waves side by side in N; each
// wave computes 64x64 via 4x4 MFMA tiles (m97 density: 16 MFMA, 8 ds_read).
// MODE 0: fp32 out + bias, XCD-swizzled 1-D grid (NB n-blocks).
// MODE 1: fp32 partial slab at z*M*N (split-K), plain 3-D grid.
template <int MODE, int NB>
__global__ __launch_bounds__(256, 3) void k_gemm(
    const u16* __restrict__ A, const u16* __restrict__ B, float* __restrict__ Out,
    const float* __restrict__ bias, int M, int N, int K) {
  __shared__ u16 As[64 * 32];    //  4 KB
  __shared__ u16 Bs[256 * 32];   // 16 KB

  const int tid = threadIdx.x;
  const int lane = tid & 63;
  const int wv = tid >> 6;
  const int waveN = wv << 6;
  const int l15 = lane & 15;
  const int quad = lane >> 4;

  long bm, bn;
  int kBeg, kEnd;
  if constexpr (MODE == 0) {
    // XCD swizzle: xcd = id%8 owns a contiguous range of m-panels; its
    // NB n-blocks per m-panel are temporally adjacent (A L2-resident).
    const int id = blockIdx.x;            // gridDim.x = (M/64)*NB
    const int xcd = id & 7;
    const int j = id >> 3;                // slot within XCD
    const int mPerXcd = M / 64 / 8;       // m-panels per XCD
    bm = (long)(xcd * mPerXcd + j / NB) * 64;
    bn = (long)(j % NB) * 256;
    kBeg = 0; kEnd = K;
  } else {
    bm = (long)blockIdx.x * 64;
    bn = (long)blockIdx.y * 256;
    const int kChunk = K / gridDim.z;
    kBeg = blockIdx.z * kChunk;
    kEnd = kBeg + kChunk;
  }

  // staging map: thread tid handles 16B = row (tid>>2), col (tid&3)*8
  const int srow = tid >> 2;
  const int scol = (tid & 3) << 3;
  const u16* Ag = A + (bm + srow) * K + scol;
  const u16* Bg = B + (bn + srow) * K + scol;
  u16* As0 = As + wv * 512;  // wave-uniform LDS bases (+lane*16B implicit)
  u16* Bs0 = Bs + wv * 512;

  const f32x4 zero = {0.f, 0.f, 0.f, 0.f};
  f32x4 acc[4][4];
#pragma unroll
  for (int i = 0; i < 4; ++i)
#pragma unroll
    for (int j = 0; j < 4; ++j) acc[i][j] = zero;

  for (int k0 = kBeg; k0 < kEnd; k0 += 32) {
    __syncthreads();  // previous tile fully consumed
    load16(Ag + k0, As0);                              // A: 64 rows
#pragma unroll
    for (int r = 0; r < 4; ++r)                        // B: 4 x 64 rows
      load16(Bg + (long)r * 64 * K + k0, Bs0 + r * 2048);
    __syncthreads();  // staging drained (vmcnt(0) before s_barrier)

    bf16x8 af[4], bg[4];
#pragma unroll
    for (int t = 0; t < 4; ++t) {
      af[t] = *(const bf16x8*)(As + (t * 16 + l15) * 32 + quad * 8);
      bg[t] = *(const bf16x8*)(Bs + (waveN + t * 16 + l15) * 32 + quad * 8);
    }
#pragma unroll
    for (int i = 0; i < 4; ++i)
#pragma unroll
      for (int j = 0; j < 4; ++j)
        acc[i][j] = __builtin_amdgcn_mfma_f32_16x16x32_bf16(af[i], bg[j], acc[i][j], 0, 0, 0);
  }

  // epilogue: C/D layout col = lane&15, row = quad*4 + reg  [m89/m91]
  float* outp = (MODE == 1) ? Out + (long)blockIdx.z * M * N : Out;
#pragma unroll
  for (int i = 0; i < 4; ++i) {
    const long gm = bm + i * 16 + quad * 4;
#pragma unroll
    for (int j = 0; j < 4; ++j) {
      const long gn = bn + waveN + j * 16 + l15;
      const float bb = (MODE == 0) ? bias[gn] : 0.f;
#pragma unroll
      for (int r = 0; r < 4; ++r)
        outp[(gm + r) * N + gn] = acc[i][j][r] + bb;
    }
  }
}

// =====================================================================
extern "C" void kernel_launch(void* const* d_in, const int* in_sizes, int n_in,
                              void* d_out, int out_size, void* d_ws, size_t ws_size,
                              hipStream_t stream) {
  // setup_inputs order: x, Wq, bq, Wk, bk, Wv, bv, Wp, bp
  const float* x  = (const float*)d_in[0];
  const float* Wv = (const float*)d_in[5];
  const float* bv = (const float*)d_in[6];
  const float* Wp = (const float*)d_in[7];
  const float* bp = (const float*)d_in[8];

  char* ws = (char*)d_ws;
  u16* xb    = (u16*)(ws);                      // 16 MB  x bf16
  u16* wpb   = (u16*)(ws + (16u << 20));        //  2 MB  Wp bf16
  u16* wvtb  = (u16*)(ws + (18u << 20));        //  2 MB  Wv^T bf16
  u16* m2b   = (u16*)(ws + (20u << 20));        //  2 MB  M2 bf16
  float* cv  = (float*)(ws + (22u << 20));      //  4 KB  folded bias
  float* m2f = (float*)(ws + (22u << 20) + 4096);  // 16 MB split-K partials

  // 1) fused prep: conv x / conv Wp / transpose Wv / bias fold
  k_prep<<<10496, 256, 0, stream>>>(x, Wv, bv, Wp, bp, xb, wpb, wvtb, cv);

  // 2) M2 partials = Wp @ Wv  (split-K=4: 16x4x4 = 256 blocks)
  k_gemm<1, 4><<<dim3(16, 4, 4), 256, 0, stream>>>(wpb, wvtb, m2f, nullptr,
                                                   1024, 1024, 1024);
  // 3) M2 = bf16(2048 * sum of partials)
  k_reduce<<<1024, 256, 0, stream>>>(m2f, m2b);

  // 4) out = x @ M2^T + cv  (128 m-panels x 4 n-blocks = 512, XCD-swizzled)
  k_gemm<0, 4><<<512, 256, 0, stream>>>(xb, m2b, (float*)d_out, cv,
                                        8192, 1024, 1024);
}

// Round 4
// 145.904 us; speedup vs baseline: 1.0521x; 1.0521x over previous
//
#include <hip/hip_runtime.h>
#include <cstdint>

// =====================================================================
// MultiHeadAttention_84576495993495  (round 4)
//
// Algebraic collapse: einsum('bhqk,bhvo->bhvo', attn, v) sums attn over
// BOTH q and k; softmax rows sum to 1 -> factor is exactly S=2048.
//   final = x @ (2048*Wp@Wv)^T + (2048*Wp@bv + bp)
// Wq/bq/Wk/bk unused.
//
// R4 changes (gemm inner loop was LDS-bank-conflict + barrier bound):
//   - XOR-swizzled LDS placement (kc ^= row&7) via per-lane global addr
//     choice at global_load_lds time; fragment reads apply the same XOR.
//     Kills the structural 8-way conflict of the m97 layout (-> 2-way=free).
//   - BK=64: 16 K-iters instead of 32 (half the vmcnt(0)+barrier drains).
//     LDS 8KB(A)+32KB(B)=40KB -> still 3 blocks/CU.
// =====================================================================

typedef unsigned short u16;
typedef __bf16 bf16x8 __attribute__((ext_vector_type(8)));
typedef float f32x4 __attribute__((ext_vector_type(4)));

__device__ __forceinline__ u16 f2bf(float f) {
  // round-to-nearest-even f32 -> bf16 bits (finite inputs)
  unsigned int u = __float_as_uint(f);
  u += 0x7fffu + ((u >> 16) & 1u);
  return (u16)(u >> 16);
}

// async global->LDS 16B copy; LDS dest = wave-uniform base + lane*16
__device__ __forceinline__ void load16(const void* g, void* l) {
  auto gp = (const __attribute__((address_space(1))) unsigned int*)(uintptr_t)g;
  auto lp = (__attribute__((address_space(3))) unsigned int*)(unsigned int)(uintptr_t)l;
  __builtin_amdgcn_global_load_lds(gp, lp, 16, 0, 0);
}

// ---------------------------------------------------------------------
// Fused prep. Block ranges:
//   [0,8192)      conv x   f32->bf16 (4 elem/thread)
//   [8192,9216)   conv Wp  f32->bf16
//   [9216,10240)  transpose+conv Wv -> Wv^T bf16 (32x32 tiles)
//   [10240,10496) cv[n] = 2048*dot(Wp[n,:],bv) + bp[n]
__global__ void k_prep(const float* __restrict__ x, const float* __restrict__ Wv,
                       const float* __restrict__ bv, const float* __restrict__ Wp,
                       const float* __restrict__ bp, u16* __restrict__ xb,
                       u16* __restrict__ wpb, u16* __restrict__ wvtb,
                       float* __restrict__ cv) {
  __shared__ float tile[32][33];
  const int b = blockIdx.x;
  const int tid = threadIdx.x;
  if (b < 9216) {  // conversions
    const float* src = (b < 8192) ? x : Wp;
    u16* dst = (b < 8192) ? xb : wpb;
    const long base = (long)((b < 8192) ? b : (b - 8192)) * 1024 + tid * 4;
    const float4 v = *(const float4*)(src + base);
    ushort4 o;
    o.x = f2bf(v.x); o.y = f2bf(v.y); o.z = f2bf(v.z); o.w = f2bf(v.w);
    *(ushort4*)(dst + base) = o;
  } else if (b < 10240) {  // transpose Wv
    const int tb = b - 9216;
    const int bi = (tb & 31) * 32;   // output row block (i)
    const int bj = (tb >> 5) * 32;   // output col block (j) = src row block
    const int tx = tid & 31;
    const int ty = tid >> 5;  // 0..7
    for (int r = ty; r < 32; r += 8)
      tile[r][tx] = Wv[(long)(bj + r) * 1024 + bi + tx];
    __syncthreads();
    for (int r = ty; r < 32; r += 8)
      wvtb[(long)(bi + r) * 1024 + bj + tx] = f2bf(tile[tx][r]);
  } else {  // bias fold
    const int row = (b - 10240) * 4 + (tid >> 6);
    const int lane = tid & 63;
    const float* w = Wp + (long)row * 1024;
    float s = 0.f;
    for (int j = lane; j < 1024; j += 64) s += w[j] * bv[j];
    for (int off = 32; off; off >>= 1) s += __shfl_down(s, off, 64);
    if (lane == 0) cv[row] = 2048.f * s + bp[row];
  }
}

// ---------------------------------------------------------------------
// reduce 4 split-K fp32 partial slabs -> bf16, *2048
__global__ void k_reduce(const float* __restrict__ p, u16* __restrict__ dst) {
  const long i = (long)(blockIdx.x * 256 + threadIdx.x) * 4;
  const float4 a = *(const float4*)(p + i);
  const float4 b = *(const float4*)(p + 1048576 + i);
  const float4 c = *(const float4*)(p + 2097152 + i);
  const float4 d = *(const float4*)(p + 3145728 + i);
  ushort4 o;
  o.x = f2bf((a.x + b.x + c.x + d.x) * 2048.f);
  o.y = f2bf((a.y + b.y + c.y + d.y) * 2048.f);
  o.z = f2bf((a.z + b.z + c.z + d.z) * 2048.f);
  o.w = f2bf((a.w + b.w + c.w + d.w) * 2048.f);
  *(ushort4*)(dst + i) = o;
}

// ---------------------------------------------------------------------
// NT bf16 GEMM: Out[M,N] (+bias) = A[M,K] @ B[N,K]^T
// BM=64, BN=256, BK=64. 256 threads = 4 waves side by side in N; each
// wave computes 64x64 via 4x4 MFMA tiles, 2 k-halves per K-iter.
// LDS is XOR-swizzled: chunk kc of row r lives at slot kc ^ (r&7)
// (8 chunks of 16B per 128B row) -> fragment ds_read_b128 is 2-way
// bank-aliased only (free), vs 8-way in the naive layout.
// MODE 0: fp32 out + bias, XCD-swizzled 1-D grid (NB n-blocks).
// MODE 1: fp32 partial slab at z*M*N (split-K), plain 3-D grid.
template <int MODE, int NB>
__global__ __launch_bounds__(256, 3) void k_gemm(
    const u16* __restrict__ A, const u16* __restrict__ B, float* __restrict__ Out,
    const float* __restrict__ bias, int M, int N, int K) {
  __shared__ u16 As[64 * 64];    //  8 KB
  __shared__ u16 Bs[256 * 64];   // 32 KB

  const int tid = threadIdx.x;
  const int lane = tid & 63;
  const int wv = tid >> 6;
  const int waveN = wv << 6;
  const int l15 = lane & 15;
  const int quad = lane >> 4;

  long bm, bn;
  int kBeg, kEnd;
  if constexpr (MODE == 0) {
    // XCD swizzle: xcd = id%8 owns a contiguous range of m-panels.
    const int id = blockIdx.x;            // gridDim.x = (M/64)*NB
    const int xcd = id & 7;
    const int j = id >> 3;
    const int mPerXcd = M / 64 / 8;
    bm = (long)(xcd * mPerXcd + j / NB) * 64;
    bn = (long)(j % NB) * 256;
    kBeg = 0; kEnd = K;
  } else {
    bm = (long)blockIdx.x * 64;
    bn = (long)blockIdx.y * 256;
    const int kChunk = K / gridDim.z;
    kBeg = blockIdx.z * kChunk;
    kEnd = kBeg + kChunk;
  }

  // staging map (per 4KB call): LDS row = base_row + tid>>3, in-row slot
  // tid&7; the GLOBAL chunk fetched is kc = (tid&7) ^ (row&7)  (XOR swizzle)
  const int srow = tid >> 3;            // 0..31
  const int sslot = tid & 7;
  const f32x4 zero = {0.f, 0.f, 0.f, 0.f};
  f32x4 acc[4][4];
#pragma unroll
  for (int i = 0; i < 4; ++i)
#pragma unroll
    for (int j = 0; j < 4; ++j) acc[i][j] = zero;

  for (int k0 = kBeg; k0 < kEnd; k0 += 64) {
    __syncthreads();  // previous tile fully consumed
#pragma unroll
    for (int r = 0; r < 2; ++r) {  // A: 64 rows x 64 k
      const int row = r * 32 + srow;
      const int kc = sslot ^ (row & 7);
      load16(A + (bm + row) * K + k0 + kc * 8, As + r * 2048 + wv * 512);
    }
#pragma unroll
    for (int r = 0; r < 8; ++r) {  // B: 256 rows x 64 k
      const int row = r * 32 + srow;
      const int kc = sslot ^ (row & 7);
      load16(B + (bn + row) * K + k0 + kc * 8, Bs + r * 2048 + wv * 512);
    }
    __syncthreads();  // staging drained (vmcnt(0) before s_barrier)

#pragma unroll
    for (int h = 0; h < 2; ++h) {
      bf16x8 af[4], bg[4];
#pragma unroll
      for (int t = 0; t < 4; ++t) {
        const int xk = ((h << 2) + quad) ^ (l15 & 7);   // swizzled chunk
        af[t] = *(const bf16x8*)(As + (t * 16 + l15) * 64 + xk * 8);
        bg[t] = *(const bf16x8*)(Bs + (waveN + t * 16 + l15) * 64 + xk * 8);
      }
#pragma unroll
      for (int i = 0; i < 4; ++i)
#pragma unroll
        for (int j = 0; j < 4; ++j)
          acc[i][j] = __builtin_amdgcn_mfma_f32_16x16x32_bf16(af[i], bg[j], acc[i][j], 0, 0, 0);
    }
  }

  // epilogue: C/D layout col = lane&15, row = quad*4 + reg  [m89/m91]
  float* outp = (MODE == 1) ? Out + (long)blockIdx.z * M * N : Out;
#pragma unroll
  for (int i = 0; i < 4; ++i) {
    const long gm = bm + i * 16 + quad * 4;
#pragma unroll
    for (int j = 0; j < 4; ++j) {
      const long gn = bn + waveN + j * 16 + l15;
      const float bb = (MODE == 0) ? bias[gn] : 0.f;
#pragma unroll
      for (int r = 0; r < 4; ++r)
        outp[(gm + r) * N + gn] = acc[i][j][r] + bb;
    }
  }
}

// =====================================================================
extern "C" void kernel_launch(void* const* d_in, const int* in_sizes, int n_in,
                              void* d_out, int out_size, void* d_ws, size_t ws_size,
                              hipStream_t stream) {
  // setup_inputs order: x, Wq, bq, Wk, bk, Wv, bv, Wp, bp
  const float* x  = (const float*)d_in[0];
  const float* Wv = (const float*)d_in[5];
  const float* bv = (const float*)d_in[6];
  const float* Wp = (const float*)d_in[7];
  const float* bp = (const float*)d_in[8];

  char* ws = (char*)d_ws;
  u16* xb    = (u16*)(ws);                      // 16 MB  x bf16
  u16* wpb   = (u16*)(ws + (16u << 20));        //  2 MB  Wp bf16
  u16* wvtb  = (u16*)(ws + (18u << 20));        //  2 MB  Wv^T bf16
  u16* m2b   = (u16*)(ws + (20u << 20));        //  2 MB  M2 bf16
  float* cv  = (float*)(ws + (22u << 20));      //  4 KB  folded bias
  float* m2f = (float*)(ws + (22u << 20) + 4096);  // 16 MB split-K partials

  // 1) fused prep: conv x / conv Wp / transpose Wv / bias fold
  k_prep<<<10496, 256, 0, stream>>>(x, Wv, bv, Wp, bp, xb, wpb, wvtb, cv);

  // 2) M2 partials = Wp @ Wv  (split-K=4: 16x4x4 = 256 blocks)
  k_gemm<1, 4><<<dim3(16, 4, 4), 256, 0, stream>>>(wpb, wvtb, m2f, nullptr,
                                                   1024, 1024, 1024);
  // 3) M2 = bf16(2048 * sum of partials)
  k_reduce<<<1024, 256, 0, stream>>>(m2f, m2b);

  // 4) out = x @ M2^T + cv  (128 m-panels x 4 n-blocks = 512, XCD-swizzled)
  k_gemm<0, 4><<<512, 256, 0, stream>>>(xb, m2b, (float*)d_out, cv,
                                        8192, 1024, 1024);
}